// Round 1
// 1804.404 us; speedup vs baseline: 1.1742x; 1.1742x over previous
//
#include <hip/hip_runtime.h>
#include <hip/hip_bf16.h>

// ---------- helpers ----------
__device__ __forceinline__ float bf2f(unsigned short u) {
    union { unsigned int i; float f; } v;
    v.i = ((unsigned int)u) << 16;
    return v.f;
}
__device__ __forceinline__ unsigned short f2bf(float f) {
    __hip_bfloat16 h = __float2bfloat16(f);   // RNE
    return *reinterpret_cast<unsigned short*>(&h);
}

// ---------- dtype probe: flag=0 -> bf16 inputs, flag=1 -> f32 inputs ----------
__global__ void probe_dtype(const unsigned short* __restrict__ x, int* flag) {
    if (blockIdx.x == 0 && threadIdx.x == 0) {
        int wild = 0;
        for (int i = 0; i < 512; ++i) {
            unsigned e = (x[i] >> 7) & 0xFF;
            if (e >= 0xC0) ++wild;
        }
        *flag = (wild > 0) ? 1 : 0;
    }
}

// ================= CSR build =================
__global__ __launch_bounds__(256) void hist_rows(
    const int* __restrict__ rows, int* __restrict__ cnt, int nnz)
{
    int e = blockIdx.x * 256 + threadIdx.x;
    if (e < nnz) atomicAdd(&cnt[rows[e]], 1);
}

// per-block (1024 elems) exclusive scan of cnt -> rp (local), block total -> bsum[b]
__global__ __launch_bounds__(256) void scan1(
    const int* __restrict__ cnt, int* __restrict__ rp, int* __restrict__ bsum, int n)
{
    __shared__ int s[256];
    const int b = blockIdx.x, t = threadIdx.x;
    const int base = b * 1024 + t * 4;
    int v[4]; int sum = 0;
#pragma unroll
    for (int j = 0; j < 4; ++j) { int i = base + j; v[j] = (i < n) ? cnt[i] : 0; sum += v[j]; }
    s[t] = sum; __syncthreads();
    for (int off = 1; off < 256; off <<= 1) {
        int xv = (t >= off) ? s[t - off] : 0;
        __syncthreads();
        s[t] += xv;
        __syncthreads();
    }
    int run = s[t] - sum;   // exclusive prefix of this thread's chunk within block
#pragma unroll
    for (int j = 0; j < 4; ++j) { int i = base + j; if (i < n) rp[i] = run; run += v[j]; }
    if (t == 255) bsum[b] = s[255];
}

// single-block exclusive scan of bsum[0..nb), nb <= 256
__global__ __launch_bounds__(256) void scan2(int* __restrict__ bsum, int nb)
{
    __shared__ int s[256];
    const int t = threadIdx.x;
    int v = (t < nb) ? bsum[t] : 0;
    s[t] = v; __syncthreads();
    for (int off = 1; off < 256; off <<= 1) {
        int xv = (t >= off) ? s[t - off] : 0;
        __syncthreads();
        s[t] += xv;
        __syncthreads();
    }
    if (t < nb) bsum[t] = s[t] - v;
}

__global__ __launch_bounds__(256) void scan3(
    int* __restrict__ rp, const int* __restrict__ bsum, int n, int nnz)
{
    int i = blockIdx.x * 256 + threadIdx.x;
    if (i < n) rp[i] += bsum[i >> 10];
    if (i == 0) rp[n] = nnz;
}

// fill sorted edge array: edges[pos] = (col, f32bits(val))
__global__ __launch_bounds__(256) void fill_edges(
    const int* __restrict__ rows, const int* __restrict__ cols,
    const void* __restrict__ vals, const int* __restrict__ flag,
    const int* __restrict__ rp, int* __restrict__ cur,
    uint2* __restrict__ edges, int nnz)
{
    int e = blockIdx.x * 256 + threadIdx.x;
    if (e >= nnz) return;
    int r = rows[e];
    int pos = rp[r] + atomicAdd(&cur[r], 1);
    float v = (*flag) ? ((const float*)vals)[e]
                      : bf2f(((const unsigned short*)vals)[e]);
    uint2 ed; ed.x = (unsigned)cols[e]; ed.y = __float_as_uint(v);
    edges[pos] = ed;
}

// ============ fused gather-SpMM (CSR) + 64x64 GEMM + epilogue ============
// block = 256 threads, owns 64 output rows. Wave w gathers rows w*16..w*16+15
// channel-per-lane (coalesced 256B x reads), deposits to LDS, then the block
// does T = xs @ W with the 4x4 microtile and applies the phase epilogue.
// mode 0: m = relu(T * cci)   (overwrite)
// mode 1: m += relu(T)        (accumulate)
__global__ __launch_bounds__(256) void spmm_gemm(
    const int* __restrict__ rp, const uint2* __restrict__ edges,
    const void* __restrict__ x, const void* __restrict__ W,
    const void* __restrict__ cci, void* mout, const int* __restrict__ flag,
    int nrows, long long mbase, int mode)
{
    __shared__ float Ws[64][64];
    __shared__ float xs[64][65];
    const int tid = threadIdx.x;
    const int fl = *flag;

    if (fl) {
        const float* Wf = (const float*)W;
        for (int i = tid; i < 4096; i += 256) Ws[i >> 6][i & 63] = Wf[i];
    } else {
        const unsigned short* Wb = (const unsigned short*)W;
        for (int i = tid; i < 4096; i += 256) Ws[i >> 6][i & 63] = bf2f(Wb[i]);
    }

    const int row0 = blockIdx.x * 64;
    const int wv   = __builtin_amdgcn_readfirstlane(tid >> 6);
    const int lane = tid & 63;

    if (fl) {
        const float* xf = (const float*)x;
        for (int i = 0; i < 16; ++i) {
            int lr = wv * 16 + i;
            int row = row0 + lr;
            float a0 = 0.f, a1 = 0.f;
            if (row < nrows) {
                int e0 = rp[row], e1 = rp[row + 1];
                int e = e0;
                for (; e + 1 < e1; e += 2) {
                    uint2 d0 = edges[e], d1 = edges[e + 1];
                    a0 += __uint_as_float(d0.y) * xf[(size_t)d0.x * 64 + lane];
                    a1 += __uint_as_float(d1.y) * xf[(size_t)d1.x * 64 + lane];
                }
                if (e < e1) {
                    uint2 d0 = edges[e];
                    a0 += __uint_as_float(d0.y) * xf[(size_t)d0.x * 64 + lane];
                }
            }
            xs[lr][lane] = a0 + a1;
        }
    } else {
        const unsigned short* xb = (const unsigned short*)x;
        for (int i = 0; i < 16; ++i) {
            int lr = wv * 16 + i;
            int row = row0 + lr;
            float a0 = 0.f, a1 = 0.f;
            if (row < nrows) {
                int e0 = rp[row], e1 = rp[row + 1];
                int e = e0;
                for (; e + 1 < e1; e += 2) {
                    uint2 d0 = edges[e], d1 = edges[e + 1];
                    a0 += __uint_as_float(d0.y) * bf2f(xb[(size_t)d0.x * 64 + lane]);
                    a1 += __uint_as_float(d1.y) * bf2f(xb[(size_t)d1.x * 64 + lane]);
                }
                if (e < e1) {
                    uint2 d0 = edges[e];
                    a0 += __uint_as_float(d0.y) * bf2f(xb[(size_t)d0.x * 64 + lane]);
                }
            }
            xs[lr][lane] = a0 + a1;
        }
    }
    __syncthreads();

    const int tx = tid & 15, ty = tid >> 4;
    float a4[4][4];
#pragma unroll
    for (int a = 0; a < 4; ++a)
#pragma unroll
        for (int b = 0; b < 4; ++b) a4[a][b] = 0.f;

#pragma unroll 8
    for (int k = 0; k < 64; ++k) {
        float4 w4 = *reinterpret_cast<const float4*>(&Ws[k][tx << 2]);
#pragma unroll
        for (int rr = 0; rr < 4; ++rr) {
            float xv = xs[ty + 16 * rr][k];
            a4[rr][0] += xv * w4.x;
            a4[rr][1] += xv * w4.y;
            a4[rr][2] += xv * w4.z;
            a4[rr][3] += xv * w4.w;
        }
    }

#pragma unroll
    for (int rr = 0; rr < 4; ++rr) {
        int l = row0 + ty + 16 * rr;
        if (l >= nrows) continue;
        size_t co = (size_t)l * 64 + (tx << 2);
        size_t ob = (size_t)mbase + co;
        float t[4] = { a4[rr][0], a4[rr][1], a4[rr][2], a4[rr][3] };
        if (mode == 0) {
            float c4[4];
            if (fl) {
                float4 cv = *reinterpret_cast<const float4*>(&((const float*)cci)[co]);
                c4[0] = cv.x; c4[1] = cv.y; c4[2] = cv.z; c4[3] = cv.w;
            } else {
                ushort4 cv = *reinterpret_cast<const ushort4*>(&((const unsigned short*)cci)[co]);
                c4[0] = bf2f(cv.x); c4[1] = bf2f(cv.y); c4[2] = bf2f(cv.z); c4[3] = bf2f(cv.w);
            }
#pragma unroll
            for (int j = 0; j < 4; ++j) t[j] = fmaxf(t[j] * c4[j], 0.f);
            if (fl) {
                float4 o; o.x = t[0]; o.y = t[1]; o.z = t[2]; o.w = t[3];
                *reinterpret_cast<float4*>(&((float*)mout)[ob]) = o;
            } else {
                ushort4 o; o.x = f2bf(t[0]); o.y = f2bf(t[1]); o.z = f2bf(t[2]); o.w = f2bf(t[3]);
                *reinterpret_cast<ushort4*>(&((unsigned short*)mout)[ob]) = o;
            }
        } else {
            if (fl) {
                float* mp = (float*)mout;
                float4 ov = *reinterpret_cast<const float4*>(&mp[ob]);
                float4 o;
                o.x = ov.x + fmaxf(t[0], 0.f);
                o.y = ov.y + fmaxf(t[1], 0.f);
                o.z = ov.z + fmaxf(t[2], 0.f);
                o.w = ov.w + fmaxf(t[3], 0.f);
                *reinterpret_cast<float4*>(&mp[ob]) = o;
            } else {
                unsigned short* mp = (unsigned short*)mout;
                ushort4 ov = *reinterpret_cast<const ushort4*>(&mp[ob]);
                ushort4 o;
                o.x = f2bf(bf2f(ov.x) + fmaxf(t[0], 0.f));
                o.y = f2bf(bf2f(ov.y) + fmaxf(t[1], 0.f));
                o.z = f2bf(bf2f(ov.z) + fmaxf(t[2], 0.f));
                o.w = f2bf(bf2f(ov.w) + fmaxf(t[3], 0.f));
                *reinterpret_cast<ushort4*>(&mp[ob]) = o;
            }
        }
    }
}

// ================= fallback path (atomic scatter, chunked) =================
__global__ __launch_bounds__(256) void scatter_x(
    const int* __restrict__ rows, const int* __restrict__ cols,
    const void* __restrict__ vals, const void* __restrict__ x,
    const int* __restrict__ flag,
    float* __restrict__ acc, int nnz, int r0, int r1)
{
    int e = blockIdx.x * 4 + threadIdx.y;
    if (e >= nnz) return;
    int r = rows[e];
    if (r < r0 || r >= r1) return;
    int c = threadIdx.x;
    int cc = cols[e];
    const int fl = *flag;
    float v, xv;
    if (fl) {
        v  = ((const float*)vals)[e];
        xv = ((const float*)x)[(size_t)cc * 64 + c];
    } else {
        v  = bf2f(((const unsigned short*)vals)[e]);
        xv = bf2f(((const unsigned short*)x)[(size_t)cc * 64 + c]);
    }
    atomicAdd(&acc[(size_t)(r - r0) * 64 + c], v * xv);
}

__global__ __launch_bounds__(256) void gemm_phase(
    const float* __restrict__ acc,
    const void* __restrict__ W,
    const void* __restrict__ cci,
    void* mout,
    const int* __restrict__ flag,
    int n_rows, long long grow0, long long mbase, int mode)
{
    __shared__ float Ws[64][64];
    __shared__ float xs[64][65];
    const int tid = threadIdx.x;
    const int tx = tid & 15, ty = tid >> 4;
    const int fl = *flag;

    if (fl) {
        const float* Wf = (const float*)W;
        for (int i = tid; i < 4096; i += 256) Ws[i >> 6][i & 63] = Wf[i];
    } else {
        const unsigned short* Wb = (const unsigned short*)W;
        for (int i = tid; i < 4096; i += 256) Ws[i >> 6][i & 63] = bf2f(Wb[i]);
    }
    const int lrow0 = blockIdx.x * 64;
    for (int i = tid; i < 4096; i += 256) {
        int r = i >> 6, c = i & 63;
        int l = lrow0 + r;
        xs[r][c] = (l < n_rows) ? acc[(size_t)l * 64 + c] : 0.f;
    }
    __syncthreads();

    float a4[4][4];
#pragma unroll
    for (int a = 0; a < 4; ++a)
#pragma unroll
        for (int b = 0; b < 4; ++b) a4[a][b] = 0.f;

#pragma unroll 8
    for (int k = 0; k < 64; ++k) {
        float4 w4 = *reinterpret_cast<const float4*>(&Ws[k][tx << 2]);
#pragma unroll
        for (int rr = 0; rr < 4; ++rr) {
            float xv = xs[ty + 16 * rr][k];
            a4[rr][0] += xv * w4.x;
            a4[rr][1] += xv * w4.y;
            a4[rr][2] += xv * w4.z;
            a4[rr][3] += xv * w4.w;
        }
    }

#pragma unroll
    for (int rr = 0; rr < 4; ++rr) {
        int l = lrow0 + ty + 16 * rr;
        if (l >= n_rows) continue;
        long long g = grow0 + l;
        size_t co = (size_t)g * 64 + (tx << 2);
        size_t ob = (size_t)mbase + co;
        float t[4] = { a4[rr][0], a4[rr][1], a4[rr][2], a4[rr][3] };
        if (mode == 0) {
            float c4[4];
            if (fl) {
                float4 cv = *reinterpret_cast<const float4*>(&((const float*)cci)[co]);
                c4[0] = cv.x; c4[1] = cv.y; c4[2] = cv.z; c4[3] = cv.w;
            } else {
                ushort4 cv = *reinterpret_cast<const ushort4*>(&((const unsigned short*)cci)[co]);
                c4[0] = bf2f(cv.x); c4[1] = bf2f(cv.y); c4[2] = bf2f(cv.z); c4[3] = bf2f(cv.w);
            }
#pragma unroll
            for (int j = 0; j < 4; ++j) t[j] = fmaxf(t[j] * c4[j], 0.f);
            if (fl) {
                float4 o; o.x = t[0]; o.y = t[1]; o.z = t[2]; o.w = t[3];
                *reinterpret_cast<float4*>(&((float*)mout)[ob]) = o;
            } else {
                ushort4 o; o.x = f2bf(t[0]); o.y = f2bf(t[1]); o.z = f2bf(t[2]); o.w = f2bf(t[3]);
                *reinterpret_cast<ushort4*>(&((unsigned short*)mout)[ob]) = o;
            }
        } else {
            if (fl) {
                float* mp = (float*)mout;
                float4 ov = *reinterpret_cast<const float4*>(&mp[ob]);
                float4 o;
                o.x = ov.x + fmaxf(t[0], 0.f);
                o.y = ov.y + fmaxf(t[1], 0.f);
                o.z = ov.z + fmaxf(t[2], 0.f);
                o.w = ov.w + fmaxf(t[3], 0.f);
                *reinterpret_cast<float4*>(&mp[ob]) = o;
            } else {
                unsigned short* mp = (unsigned short*)mout;
                ushort4 ov = *reinterpret_cast<const ushort4*>(&mp[ob]);
                ushort4 o;
                o.x = f2bf(bf2f(ov.x) + fmaxf(t[0], 0.f));
                o.y = f2bf(bf2f(ov.y) + fmaxf(t[1], 0.f));
                o.z = f2bf(bf2f(ov.z) + fmaxf(t[2], 0.f));
                o.w = f2bf(bf2f(ov.w) + fmaxf(t[3], 0.f));
                *reinterpret_cast<ushort4*>(&mp[ob]) = o;
            }
        }
    }
}

// ---------- finalize: out = relu(m @ Wg) ----------
__global__ __launch_bounds__(256) void finalize(
    void* mout, const void* __restrict__ Wg, const int* __restrict__ flag,
    int N, long long mbase)
{
    __shared__ float Ws[64][64];
    __shared__ float ms[64][65];
    const int tid = threadIdx.x;
    const int tx = tid & 15, ty = tid >> 4;
    const int fl = *flag;

    if (fl) {
        const float* Wf = (const float*)Wg;
        for (int i = tid; i < 4096; i += 256) Ws[i >> 6][i & 63] = Wf[i];
    } else {
        const unsigned short* Wb = (const unsigned short*)Wg;
        for (int i = tid; i < 4096; i += 256) Ws[i >> 6][i & 63] = bf2f(Wb[i]);
    }
    const int row0 = blockIdx.x * 64;
    for (int i = tid; i < 4096; i += 256) {
        int r = i >> 6, c = i & 63;
        int g = row0 + r;
        float v = 0.f;
        if (g < N) {
            size_t o = (size_t)mbase + (size_t)g * 64 + c;
            v = fl ? ((const float*)mout)[o] : bf2f(((const unsigned short*)mout)[o]);
        }
        ms[r][c] = v;
    }
    __syncthreads();

    float a4[4][4];
#pragma unroll
    for (int a = 0; a < 4; ++a)
#pragma unroll
        for (int b = 0; b < 4; ++b) a4[a][b] = 0.f;

#pragma unroll 8
    for (int k = 0; k < 64; ++k) {
        float4 w4 = *reinterpret_cast<const float4*>(&Ws[k][tx << 2]);
#pragma unroll
        for (int rr = 0; rr < 4; ++rr) {
            float xv = ms[ty + 16 * rr][k];
            a4[rr][0] += xv * w4.x;
            a4[rr][1] += xv * w4.y;
            a4[rr][2] += xv * w4.z;
            a4[rr][3] += xv * w4.w;
        }
    }
#pragma unroll
    for (int rr = 0; rr < 4; ++rr) {
        int g = row0 + ty + 16 * rr;
        if (g >= N) continue;
        size_t ob = (size_t)mbase + (size_t)g * 64 + (tx << 2);
        if (fl) {
            float4 o;
            o.x = fmaxf(a4[rr][0], 0.f); o.y = fmaxf(a4[rr][1], 0.f);
            o.z = fmaxf(a4[rr][2], 0.f); o.w = fmaxf(a4[rr][3], 0.f);
            *reinterpret_cast<float4*>(&((float*)mout)[ob]) = o;
        } else {
            ushort4 o;
            o.x = f2bf(fmaxf(a4[rr][0], 0.f)); o.y = f2bf(fmaxf(a4[rr][1], 0.f));
            o.z = f2bf(fmaxf(a4[rr][2], 0.f)); o.w = f2bf(fmaxf(a4[rr][3], 0.f));
            *reinterpret_cast<ushort4*>(&((unsigned short*)mout)[ob]) = o;
        }
    }
}

extern "C" void kernel_launch(void* const* d_in, const int* in_sizes, int n_in,
                              void* d_out, int out_size, void* d_ws, size_t ws_size,
                              hipStream_t stream)
{
    static const int Ns[5] = {50000, 150000, 100000, 40000, 10000};

    // ---- input pointer map (setup_inputs dict order) ----
    const void *x[5], *av[5], *cci[5], *Whbs[5], *Wagg[5];
    const int *ar[5], *ac[5];
    int nnzA[5];
    for (int r = 0; r < 5; ++r) {
        x[r]    = d_in[r * 7 + 0];
        ar[r]   = (const int*)d_in[r * 7 + 1];
        ac[r]   = (const int*)d_in[r * 7 + 2];
        av[r]   = d_in[r * 7 + 3];
        cci[r]  = d_in[r * 7 + 4];
        Whbs[r] = d_in[r * 7 + 5];
        Wagg[r] = d_in[r * 7 + 6];
        nnzA[r] = in_sizes[r * 7 + 3];
    }
    const int *it[4], *is[4];
    const void *iv[4], *Wsp[4], *Wtp[4];
    int nnzI[4];
    for (int k = 0; k < 4; ++k) {
        it[k]  = (const int*)d_in[35 + k * 5 + 0];
        is[k]  = (const int*)d_in[35 + k * 5 + 1];
        iv[k]  = d_in[35 + k * 5 + 2];
        Wsp[k] = d_in[35 + k * 5 + 3];
        Wtp[k] = d_in[35 + k * 5 + 4];
        nnzI[k] = in_sizes[35 + k * 5 + 2];
    }

    char* ws = (char*)d_ws;
    size_t flag_off = (ws_size >= 4096) ? ((ws_size - 4) & ~(size_t)3) : 0;
    int* flag = (int*)(ws + flag_off);

    probe_dtype<<<1, 64, 0, stream>>>((const unsigned short*)x[0], flag);

    dim3 b256(256);
    dim3 sb(64, 4);
    long long base = 0;   // element offset of this rank's chunk in d_out

    for (int r = 0; r < 5; ++r) {
        const int N = Ns[r];

        // phase table: {rows, cols, vals, xsrc, W, nnz, mode}
        struct Ph { const int* rw; const int* cl; const void* vl; const void* xs;
                    const void* W; int nnz; int mode; };
        Ph ph[3]; int np = 0;
        ph[np++] = { ar[r], ac[r], av[r], x[r], Whbs[r], nnzA[r], 0 };                        // same-rank
        if (r < 4) ph[np++] = { it[r], is[r], iv[r], x[r + 1], Wsp[r], nnzI[r], 1 };          // down
        if (r > 0) ph[np++] = { is[r-1], it[r-1], iv[r-1], x[r - 1], Wtp[r-1], nnzI[r-1], 1 };// up

        for (int p = 0; p < np; ++p) {
            const int nnz = ph[p].nnz;
            // CSR workspace layout: [cnt N][rp N+1][bsum 1024][edges nnz*8]
            size_t cntOff = 0;
            size_t rpOff  = ((size_t)N * 4 + 7) & ~(size_t)7;
            size_t bsOff  = rpOff + ((((size_t)N + 1) * 4 + 7) & ~(size_t)7);
            size_t edOff  = bsOff + 4096;
            size_t need   = edOff + (size_t)nnz * 8;

            if (need + 64 <= flag_off) {
                // ---- CSR gather path (no atomics in the hot loop) ----
                int*   cnt = (int*)(ws + cntOff);
                int*   rp  = (int*)(ws + rpOff);
                int*   bs  = (int*)(ws + bsOff);
                uint2* ed  = (uint2*)(ws + edOff);
                const int nb = (N + 1023) / 1024;

                hipMemsetAsync(cnt, 0, (size_t)N * 4, stream);
                hist_rows<<<(nnz + 255) / 256, b256, 0, stream>>>(ph[p].rw, cnt, nnz);
                scan1<<<nb, b256, 0, stream>>>(cnt, rp, bs, N);
                scan2<<<1, b256, 0, stream>>>(bs, nb);
                scan3<<<(N + 255) / 256, b256, 0, stream>>>(rp, bs, N, nnz);
                hipMemsetAsync(cnt, 0, (size_t)N * 4, stream);
                fill_edges<<<(nnz + 255) / 256, b256, 0, stream>>>(
                    ph[p].rw, ph[p].cl, ph[p].vl, flag, rp, cnt, ed, nnz);
                spmm_gemm<<<(N + 63) / 64, b256, 0, stream>>>(
                    rp, ed, ph[p].xs, ph[p].W, cci[r], d_out, flag,
                    N, base, ph[p].mode);
            } else {
                // ---- fallback: chunked atomic scatter + GEMM ----
                long long budget = (long long)((flag_off - 256) / 256);
                budget &= ~63LL;
                if (budget < 64) budget = 64;
                float* acc = (float*)ws;
                for (long long r0 = 0; r0 < N; r0 += budget) {
                    int rc = (int)((N - r0 < budget) ? (N - r0) : budget);
                    hipMemsetAsync(acc, 0, (size_t)rc * 256, stream);
                    scatter_x<<<(nnz + 3) / 4, sb, 0, stream>>>(
                        ph[p].rw, ph[p].cl, ph[p].vl, ph[p].xs, flag,
                        acc, nnz, (int)r0, (int)(r0 + rc));
                    gemm_phase<<<(rc + 63) / 64, b256, 0, stream>>>(
                        acc, ph[p].W, cci[r], d_out, flag,
                        rc, r0, base, ph[p].mode);
                }
            }
        }
        finalize<<<(N + 63) / 64, b256, 0, stream>>>(d_out, Wagg[r], flag, N, base);
        base += (long long)N * 64;
    }
}

// Round 2
// 1555.182 us; speedup vs baseline: 1.3623x; 1.1603x over previous
//
#include <hip/hip_runtime.h>
#include <hip/hip_bf16.h>

// ---------- helpers ----------
__device__ __forceinline__ float bf2f(unsigned short u) {
    union { unsigned int i; float f; } v;
    v.i = ((unsigned int)u) << 16;
    return v.f;
}
__device__ __forceinline__ unsigned short f2bf(float f) {
    __hip_bfloat16 h = __float2bfloat16(f);   // RNE
    return *reinterpret_cast<unsigned short*>(&h);
}
// LDS column swizzle: spreads rows ty..ty+3 across banks without +1 padding
__device__ __forceinline__ int xc(int r, int c) { return c ^ ((r & 3) << 3); }

// ---------- dtype probe: flag=0 -> bf16 inputs, flag=1 -> f32 inputs ----------
__global__ void probe_dtype(const unsigned short* __restrict__ x, int* flag) {
    if (blockIdx.x == 0 && threadIdx.x == 0) {
        int wild = 0;
        for (int i = 0; i < 512; ++i) {
            unsigned e = (x[i] >> 7) & 0xFF;
            if (e >= 0xC0) ++wild;
        }
        *flag = (wild > 0) ? 1 : 0;
    }
}

// ================= batched CSR build (gridDim.y = phase) =================
struct Seg {
    const int*  rows;
    const int*  cols;
    const void* vals;
    int*  cnt;
    int*  rp;
    int*  bsum;
    uint2* ed;
    int nnz;
    int n;
};
struct Seg3 { Seg s[3]; };

__global__ __launch_bounds__(256) void hist_all(Seg3 B) {
    Seg S = B.s[blockIdx.y];
    int e = blockIdx.x * 256 + threadIdx.x;
    if (e < S.nnz) atomicAdd(&S.cnt[S.rows[e]], 1);
}

// per-1024-chunk exclusive scan; rp gets block-local prefix, bsum[b] = block sum
__global__ __launch_bounds__(256) void scan1_all(Seg3 B) {
    Seg S = B.s[blockIdx.y];
    __shared__ int sm[256];
    const int t = threadIdx.x;
    const int base = blockIdx.x * 1024 + t * 4;
    int v[4]; int sum = 0;
#pragma unroll
    for (int j = 0; j < 4; ++j) { int i = base + j; v[j] = (i < S.n) ? S.cnt[i] : 0; sum += v[j]; }
    sm[t] = sum; __syncthreads();
    for (int off = 1; off < 256; off <<= 1) {
        int xv = (t >= off) ? sm[t - off] : 0;
        __syncthreads();
        sm[t] += xv;
        __syncthreads();
    }
    int run = sm[t] - sum;
#pragma unroll
    for (int j = 0; j < 4; ++j) { int i = base + j; if (i < S.n) S.rp[i] = run; run += v[j]; }
    if (t == 255) S.bsum[blockIdx.x] = sm[255];
}

// add cross-block offsets (parallel reduce over preceding bsum groups)
__global__ __launch_bounds__(256) void scan2_all(Seg3 B) {
    Seg S = B.s[blockIdx.y];
    __shared__ int red[256];
    const int t = threadIdx.x;
    const int g0 = blockIdx.x >> 2;   // bsum group of this 256-chunk
    int v = (t < g0) ? S.bsum[t] : 0;
    red[t] = v; __syncthreads();
    for (int o = 128; o; o >>= 1) { if (t < o) red[t] += red[t + o]; __syncthreads(); }
    int i = blockIdx.x * 256 + t;
    if (i < S.n) S.rp[i] += red[0];
}

// fill sorted edges; atomicAdd on rp itself -> afterwards rp[r] = END of row r
// (row r spans [r ? rp[r-1] : 0, rp[r]))
__global__ __launch_bounds__(256) void fill_all(Seg3 B, const int* __restrict__ flag) {
    Seg S = B.s[blockIdx.y];
    int e = blockIdx.x * 256 + threadIdx.x;
    if (e >= S.nnz) return;
    int r = S.rows[e];
    int pos = atomicAdd(&S.rp[r], 1);
    float v = (*flag) ? ((const float*)S.vals)[e]
                      : bf2f(((const unsigned short*)S.vals)[e]);
    uint2 ed; ed.x = (unsigned)S.cols[e]; ed.y = __float_as_uint(v);
    S.ed[pos] = ed;
}

// ================= MLP gather: 16 rows per wave, 8-deep load batches =================
template<int FL>
__device__ __forceinline__ void gather16(
    const int* __restrict__ rp, const uint2* __restrict__ ed,
    const void* __restrict__ x, float xsh[64][64],
    int row0, int nrows, int wv, int lane)
{
    const int rbase = row0 + wv * 16;
    // lanes 0..16 fetch the 17 row bounds once; rows get them via shfl
    int rv = 0;
    {
        int t = rbase - 1 + lane;
        if (lane <= 16 && t >= 0 && t < nrows) rv = rp[t];
    }
    for (int i = 0; i < 16; ++i) {
        int row = rbase + i;
        int e0 = __shfl(rv, i, 64);
        int e1 = __shfl(rv, i + 1, 64);
        float acc = 0.f;
        if (row < nrows) {
            for (int e = e0; e < e1; e += 8) {
                uint2 d[8];
#pragma unroll
                for (int j = 0; j < 8; ++j) {
                    int idx = e + j;
                    idx = (idx < e1) ? idx : (e1 - 1);   // clamp: branch-free, always valid
                    d[j] = ed[idx];
                }
                float xv[8];
#pragma unroll
                for (int j = 0; j < 8; ++j) {
                    size_t off = (size_t)d[j].x * 64 + lane;
                    xv[j] = FL ? ((const float*)x)[off]
                               : bf2f(((const unsigned short*)x)[off]);
                }
#pragma unroll
                for (int j = 0; j < 8; ++j) {
                    float v = (e + j < e1) ? __uint_as_float(d[j].y) : 0.f;
                    acc = fmaf(v, xv[j], acc);
                }
            }
        }
        xsh[wv * 16 + i][xc(wv * 16 + i, lane)] = acc;
    }
}

// ================= fused per-rank kernel =================
// per 64-row block: for each phase p: gather -> LDS -> T = xs@W_p -> C += relu(...)
// then out = relu(C @ Wg). m never touches HBM.
struct RankArgs {
    const int*   rp[3];
    const uint2* ed[3];
    const void*  xsrc[3];
    const void*  W[3];
    const void*  cci;
    const void*  Wg;
    long long    mbase;
    int          nrows;
    int          nph;
};

__global__ __launch_bounds__(256, 4) void rank_fused(
    RankArgs A, void* __restrict__ dout, const int* __restrict__ flag)
{
    __shared__ float Ws[64][64];
    __shared__ float xsh[64][64];
    const int tid = threadIdx.x;
    const int fl = *flag;
    const int row0 = blockIdx.x * 64;
    const int wv   = __builtin_amdgcn_readfirstlane(tid >> 6);
    const int lane = tid & 63;
    const int tx = tid & 15, ty = tid >> 4;

    float C[4][4];
#pragma unroll
    for (int a = 0; a < 4; ++a)
#pragma unroll
        for (int b = 0; b < 4; ++b) C[a][b] = 0.f;

    for (int p = 0; p < A.nph; ++p) {
        __syncthreads();   // previous phase done reading LDS
        if (fl) {
            const float* Wf = (const float*)A.W[p];
            for (int i = tid; i < 4096; i += 256) Ws[i >> 6][i & 63] = Wf[i];
        } else {
            const unsigned short* Wb = (const unsigned short*)A.W[p];
            for (int i = tid; i < 4096; i += 256) Ws[i >> 6][i & 63] = bf2f(Wb[i]);
        }
        if (fl) gather16<1>(A.rp[p], A.ed[p], A.xsrc[p], xsh, row0, A.nrows, wv, lane);
        else    gather16<0>(A.rp[p], A.ed[p], A.xsrc[p], xsh, row0, A.nrows, wv, lane);
        __syncthreads();

        float a4[4][4];
#pragma unroll
        for (int a = 0; a < 4; ++a)
#pragma unroll
            for (int b = 0; b < 4; ++b) a4[a][b] = 0.f;

#pragma unroll 8
        for (int k = 0; k < 64; ++k) {
            float4 w4 = *reinterpret_cast<const float4*>(&Ws[k][tx << 2]);
#pragma unroll
            for (int rr = 0; rr < 4; ++rr) {
                int r = ty + 16 * rr;
                float xv = xsh[r][xc(r, k)];
                a4[rr][0] += xv * w4.x;
                a4[rr][1] += xv * w4.y;
                a4[rr][2] += xv * w4.z;
                a4[rr][3] += xv * w4.w;
            }
        }

        if (p == 0) {   // same-rank: C += relu(T * cci)
#pragma unroll
            for (int rr = 0; rr < 4; ++rr) {
                int l = row0 + ty + 16 * rr;
                if (l >= A.nrows) continue;
                size_t co = (size_t)l * 64 + (tx << 2);
                float c4[4];
                if (fl) {
                    float4 cv = *reinterpret_cast<const float4*>(&((const float*)A.cci)[co]);
                    c4[0] = cv.x; c4[1] = cv.y; c4[2] = cv.z; c4[3] = cv.w;
                } else {
                    ushort4 cv = *reinterpret_cast<const ushort4*>(&((const unsigned short*)A.cci)[co]);
                    c4[0] = bf2f(cv.x); c4[1] = bf2f(cv.y); c4[2] = bf2f(cv.z); c4[3] = bf2f(cv.w);
                }
#pragma unroll
                for (int j = 0; j < 4; ++j) C[rr][j] += fmaxf(a4[rr][j] * c4[j], 0.f);
            }
        } else {        // C += relu(T)
#pragma unroll
            for (int rr = 0; rr < 4; ++rr)
#pragma unroll
                for (int j = 0; j < 4; ++j) C[rr][j] += fmaxf(a4[rr][j], 0.f);
        }
    }

    // ---- finalize in-block: out = relu(C @ Wg) ----
    __syncthreads();
#pragma unroll
    for (int rr = 0; rr < 4; ++rr) {
        int r = ty + 16 * rr;
#pragma unroll
        for (int j = 0; j < 4; ++j) xsh[r][xc(r, (tx << 2) + j)] = C[rr][j];
    }
    if (fl) {
        const float* Wf = (const float*)A.Wg;
        for (int i = tid; i < 4096; i += 256) Ws[i >> 6][i & 63] = Wf[i];
    } else {
        const unsigned short* Wb = (const unsigned short*)A.Wg;
        for (int i = tid; i < 4096; i += 256) Ws[i >> 6][i & 63] = bf2f(Wb[i]);
    }
    __syncthreads();

    float a4[4][4];
#pragma unroll
    for (int a = 0; a < 4; ++a)
#pragma unroll
        for (int b = 0; b < 4; ++b) a4[a][b] = 0.f;
#pragma unroll 8
    for (int k = 0; k < 64; ++k) {
        float4 w4 = *reinterpret_cast<const float4*>(&Ws[k][tx << 2]);
#pragma unroll
        for (int rr = 0; rr < 4; ++rr) {
            int r = ty + 16 * rr;
            float xv = xsh[r][xc(r, k)];
            a4[rr][0] += xv * w4.x;
            a4[rr][1] += xv * w4.y;
            a4[rr][2] += xv * w4.z;
            a4[rr][3] += xv * w4.w;
        }
    }
#pragma unroll
    for (int rr = 0; rr < 4; ++rr) {
        int l = row0 + ty + 16 * rr;
        if (l >= A.nrows) continue;
        size_t ob = (size_t)A.mbase + (size_t)l * 64 + (tx << 2);
        if (fl) {
            float4 o;
            o.x = fmaxf(a4[rr][0], 0.f); o.y = fmaxf(a4[rr][1], 0.f);
            o.z = fmaxf(a4[rr][2], 0.f); o.w = fmaxf(a4[rr][3], 0.f);
            *reinterpret_cast<float4*>(&((float*)dout)[ob]) = o;
        } else {
            ushort4 o;
            o.x = f2bf(fmaxf(a4[rr][0], 0.f)); o.y = f2bf(fmaxf(a4[rr][1], 0.f));
            o.z = f2bf(fmaxf(a4[rr][2], 0.f)); o.w = f2bf(fmaxf(a4[rr][3], 0.f));
            *reinterpret_cast<ushort4*>(&((unsigned short*)dout)[ob]) = o;
        }
    }
}

// ================= tier-3: per-phase CSR spmm (shifted rp convention) =================
__global__ __launch_bounds__(256, 4) void spmm_gemm(
    const int* __restrict__ rp, const uint2* __restrict__ edges,
    const void* __restrict__ x, const void* __restrict__ W,
    const void* __restrict__ cci, void* mout, const int* __restrict__ flag,
    int nrows, long long mbase, int mode)
{
    __shared__ float Ws[64][64];
    __shared__ float xsh[64][64];
    const int tid = threadIdx.x;
    const int fl = *flag;
    const int row0 = blockIdx.x * 64;
    const int wv   = __builtin_amdgcn_readfirstlane(tid >> 6);
    const int lane = tid & 63;

    if (fl) {
        const float* Wf = (const float*)W;
        for (int i = tid; i < 4096; i += 256) Ws[i >> 6][i & 63] = Wf[i];
    } else {
        const unsigned short* Wb = (const unsigned short*)W;
        for (int i = tid; i < 4096; i += 256) Ws[i >> 6][i & 63] = bf2f(Wb[i]);
    }
    if (fl) gather16<1>(rp, edges, x, xsh, row0, nrows, wv, lane);
    else    gather16<0>(rp, edges, x, xsh, row0, nrows, wv, lane);
    __syncthreads();

    const int tx = tid & 15, ty = tid >> 4;
    float a4[4][4];
#pragma unroll
    for (int a = 0; a < 4; ++a)
#pragma unroll
        for (int b = 0; b < 4; ++b) a4[a][b] = 0.f;

#pragma unroll 8
    for (int k = 0; k < 64; ++k) {
        float4 w4 = *reinterpret_cast<const float4*>(&Ws[k][tx << 2]);
#pragma unroll
        for (int rr = 0; rr < 4; ++rr) {
            int r = ty + 16 * rr;
            float xv = xsh[r][xc(r, k)];
            a4[rr][0] += xv * w4.x;
            a4[rr][1] += xv * w4.y;
            a4[rr][2] += xv * w4.z;
            a4[rr][3] += xv * w4.w;
        }
    }

#pragma unroll
    for (int rr = 0; rr < 4; ++rr) {
        int l = row0 + ty + 16 * rr;
        if (l >= nrows) continue;
        size_t co = (size_t)l * 64 + (tx << 2);
        size_t ob = (size_t)mbase + co;
        float t[4] = { a4[rr][0], a4[rr][1], a4[rr][2], a4[rr][3] };
        if (mode == 0) {
            float c4[4];
            if (fl) {
                float4 cv = *reinterpret_cast<const float4*>(&((const float*)cci)[co]);
                c4[0] = cv.x; c4[1] = cv.y; c4[2] = cv.z; c4[3] = cv.w;
            } else {
                ushort4 cv = *reinterpret_cast<const ushort4*>(&((const unsigned short*)cci)[co]);
                c4[0] = bf2f(cv.x); c4[1] = bf2f(cv.y); c4[2] = bf2f(cv.z); c4[3] = bf2f(cv.w);
            }
#pragma unroll
            for (int j = 0; j < 4; ++j) t[j] = fmaxf(t[j] * c4[j], 0.f);
            if (fl) {
                float4 o; o.x = t[0]; o.y = t[1]; o.z = t[2]; o.w = t[3];
                *reinterpret_cast<float4*>(&((float*)mout)[ob]) = o;
            } else {
                ushort4 o; o.x = f2bf(t[0]); o.y = f2bf(t[1]); o.z = f2bf(t[2]); o.w = f2bf(t[3]);
                *reinterpret_cast<ushort4*>(&((unsigned short*)mout)[ob]) = o;
            }
        } else {
            if (fl) {
                float* mp = (float*)mout;
                float4 ov = *reinterpret_cast<const float4*>(&mp[ob]);
                float4 o;
                o.x = ov.x + fmaxf(t[0], 0.f);
                o.y = ov.y + fmaxf(t[1], 0.f);
                o.z = ov.z + fmaxf(t[2], 0.f);
                o.w = ov.w + fmaxf(t[3], 0.f);
                *reinterpret_cast<float4*>(&mp[ob]) = o;
            } else {
                unsigned short* mp = (unsigned short*)mout;
                ushort4 ov = *reinterpret_cast<const ushort4*>(&mp[ob]);
                ushort4 o;
                o.x = f2bf(bf2f(ov.x) + fmaxf(t[0], 0.f));
                o.y = f2bf(bf2f(ov.y) + fmaxf(t[1], 0.f));
                o.z = f2bf(bf2f(ov.z) + fmaxf(t[2], 0.f));
                o.w = f2bf(bf2f(ov.w) + fmaxf(t[3], 0.f));
                *reinterpret_cast<ushort4*>(&mp[ob]) = o;
            }
        }
    }
}

// ---------- tier-3 finalize: out = relu(m @ Wg), m aliases out ----------
__global__ __launch_bounds__(256) void finalize(
    void* mout, const void* __restrict__ Wg, const int* __restrict__ flag,
    int N, long long mbase)
{
    __shared__ float Ws[64][64];
    __shared__ float ms[64][65];
    const int tid = threadIdx.x;
    const int tx = tid & 15, ty = tid >> 4;
    const int fl = *flag;

    if (fl) {
        const float* Wf = (const float*)Wg;
        for (int i = tid; i < 4096; i += 256) Ws[i >> 6][i & 63] = Wf[i];
    } else {
        const unsigned short* Wb = (const unsigned short*)Wg;
        for (int i = tid; i < 4096; i += 256) Ws[i >> 6][i & 63] = bf2f(Wb[i]);
    }
    const int row0 = blockIdx.x * 64;
    for (int i = tid; i < 4096; i += 256) {
        int r = i >> 6, c = i & 63;
        int g = row0 + r;
        float v = 0.f;
        if (g < N) {
            size_t o = (size_t)mbase + (size_t)g * 64 + c;
            v = fl ? ((const float*)mout)[o] : bf2f(((const unsigned short*)mout)[o]);
        }
        ms[r][c] = v;
    }
    __syncthreads();

    float a4[4][4];
#pragma unroll
    for (int a = 0; a < 4; ++a)
#pragma unroll
        for (int b = 0; b < 4; ++b) a4[a][b] = 0.f;

#pragma unroll 8
    for (int k = 0; k < 64; ++k) {
        float4 w4 = *reinterpret_cast<const float4*>(&Ws[k][tx << 2]);
#pragma unroll
        for (int rr = 0; rr < 4; ++rr) {
            float xv = ms[ty + 16 * rr][k];
            a4[rr][0] += xv * w4.x;
            a4[rr][1] += xv * w4.y;
            a4[rr][2] += xv * w4.z;
            a4[rr][3] += xv * w4.w;
        }
    }
#pragma unroll
    for (int rr = 0; rr < 4; ++rr) {
        int g = row0 + ty + 16 * rr;
        if (g >= N) continue;
        size_t ob = (size_t)mbase + (size_t)g * 64 + (tx << 2);
        if (fl) {
            float4 o;
            o.x = fmaxf(a4[rr][0], 0.f); o.y = fmaxf(a4[rr][1], 0.f);
            o.z = fmaxf(a4[rr][2], 0.f); o.w = fmaxf(a4[rr][3], 0.f);
            *reinterpret_cast<float4*>(&((float*)mout)[ob]) = o;
        } else {
            ushort4 o;
            o.x = f2bf(fmaxf(a4[rr][0], 0.f)); o.y = f2bf(fmaxf(a4[rr][1], 0.f));
            o.z = f2bf(fmaxf(a4[rr][2], 0.f)); o.w = f2bf(fmaxf(a4[rr][3], 0.f));
            *reinterpret_cast<ushort4*>(&((unsigned short*)mout)[ob]) = o;
        }
    }
}

// ================= tier-4 fallback (atomic scatter, chunked) =================
__global__ __launch_bounds__(256) void scatter_x(
    const int* __restrict__ rows, const int* __restrict__ cols,
    const void* __restrict__ vals, const void* __restrict__ x,
    const int* __restrict__ flag,
    float* __restrict__ acc, int nnz, int r0, int r1)
{
    int e = blockIdx.x * 4 + threadIdx.y;
    if (e >= nnz) return;
    int r = rows[e];
    if (r < r0 || r >= r1) return;
    int c = threadIdx.x;
    int cc = cols[e];
    const int fl = *flag;
    float v, xv;
    if (fl) {
        v  = ((const float*)vals)[e];
        xv = ((const float*)x)[(size_t)cc * 64 + c];
    } else {
        v  = bf2f(((const unsigned short*)vals)[e]);
        xv = bf2f(((const unsigned short*)x)[(size_t)cc * 64 + c]);
    }
    atomicAdd(&acc[(size_t)(r - r0) * 64 + c], v * xv);
}

__global__ __launch_bounds__(256) void gemm_phase(
    const float* __restrict__ acc,
    const void* __restrict__ W,
    const void* __restrict__ cci,
    void* mout,
    const int* __restrict__ flag,
    int n_rows, long long grow0, long long mbase, int mode)
{
    __shared__ float Ws[64][64];
    __shared__ float xs[64][65];
    const int tid = threadIdx.x;
    const int tx = tid & 15, ty = tid >> 4;
    const int fl = *flag;

    if (fl) {
        const float* Wf = (const float*)W;
        for (int i = tid; i < 4096; i += 256) Ws[i >> 6][i & 63] = Wf[i];
    } else {
        const unsigned short* Wb = (const unsigned short*)W;
        for (int i = tid; i < 4096; i += 256) Ws[i >> 6][i & 63] = bf2f(Wb[i]);
    }
    const int lrow0 = blockIdx.x * 64;
    for (int i = tid; i < 4096; i += 256) {
        int r = i >> 6, c = i & 63;
        int l = lrow0 + r;
        xs[r][c] = (l < n_rows) ? acc[(size_t)l * 64 + c] : 0.f;
    }
    __syncthreads();

    float a4[4][4];
#pragma unroll
    for (int a = 0; a < 4; ++a)
#pragma unroll
        for (int b = 0; b < 4; ++b) a4[a][b] = 0.f;

#pragma unroll 8
    for (int k = 0; k < 64; ++k) {
        float4 w4 = *reinterpret_cast<const float4*>(&Ws[k][tx << 2]);
#pragma unroll
        for (int rr = 0; rr < 4; ++rr) {
            float xv = xs[ty + 16 * rr][k];
            a4[rr][0] += xv * w4.x;
            a4[rr][1] += xv * w4.y;
            a4[rr][2] += xv * w4.z;
            a4[rr][3] += xv * w4.w;
        }
    }

#pragma unroll
    for (int rr = 0; rr < 4; ++rr) {
        int l = lrow0 + ty + 16 * rr;
        if (l >= n_rows) continue;
        long long g = grow0 + l;
        size_t co = (size_t)g * 64 + (tx << 2);
        size_t ob = (size_t)mbase + co;
        float t[4] = { a4[rr][0], a4[rr][1], a4[rr][2], a4[rr][3] };
        if (mode == 0) {
            float c4[4];
            if (fl) {
                float4 cv = *reinterpret_cast<const float4*>(&((const float*)cci)[co]);
                c4[0] = cv.x; c4[1] = cv.y; c4[2] = cv.z; c4[3] = cv.w;
            } else {
                ushort4 cv = *reinterpret_cast<const ushort4*>(&((const unsigned short*)cci)[co]);
                c4[0] = bf2f(cv.x); c4[1] = bf2f(cv.y); c4[2] = bf2f(cv.z); c4[3] = bf2f(cv.w);
            }
#pragma unroll
            for (int j = 0; j < 4; ++j) t[j] = fmaxf(t[j] * c4[j], 0.f);
            if (fl) {
                float4 o; o.x = t[0]; o.y = t[1]; o.z = t[2]; o.w = t[3];
                *reinterpret_cast<float4*>(&((float*)mout)[ob]) = o;
            } else {
                ushort4 o; o.x = f2bf(t[0]); o.y = f2bf(t[1]); o.z = f2bf(t[2]); o.w = f2bf(t[3]);
                *reinterpret_cast<ushort4*>(&((unsigned short*)mout)[ob]) = o;
            }
        } else {
            if (fl) {
                float* mp = (float*)mout;
                float4 ov = *reinterpret_cast<const float4*>(&mp[ob]);
                float4 o;
                o.x = ov.x + fmaxf(t[0], 0.f);
                o.y = ov.y + fmaxf(t[1], 0.f);
                o.z = ov.z + fmaxf(t[2], 0.f);
                o.w = ov.w + fmaxf(t[3], 0.f);
                *reinterpret_cast<float4*>(&mp[ob]) = o;
            } else {
                unsigned short* mp = (unsigned short*)mout;
                ushort4 ov = *reinterpret_cast<const ushort4*>(&mp[ob]);
                ushort4 o;
                o.x = f2bf(bf2f(ov.x) + fmaxf(t[0], 0.f));
                o.y = f2bf(bf2f(ov.y) + fmaxf(t[1], 0.f));
                o.z = f2bf(bf2f(ov.z) + fmaxf(t[2], 0.f));
                o.w = f2bf(bf2f(ov.w) + fmaxf(t[3], 0.f));
                *reinterpret_cast<ushort4*>(&mp[ob]) = o;
            }
        }
    }
}

extern "C" void kernel_launch(void* const* d_in, const int* in_sizes, int n_in,
                              void* d_out, int out_size, void* d_ws, size_t ws_size,
                              hipStream_t stream)
{
    static const int Ns[5] = {50000, 150000, 100000, 40000, 10000};

    // ---- input pointer map (setup_inputs dict order) ----
    const void *x[5], *av[5], *cci[5], *Whbs[5], *Wagg[5];
    const int *ar[5], *ac[5];
    int nnzA[5];
    for (int r = 0; r < 5; ++r) {
        x[r]    = d_in[r * 7 + 0];
        ar[r]   = (const int*)d_in[r * 7 + 1];
        ac[r]   = (const int*)d_in[r * 7 + 2];
        av[r]   = d_in[r * 7 + 3];
        cci[r]  = d_in[r * 7 + 4];
        Whbs[r] = d_in[r * 7 + 5];
        Wagg[r] = d_in[r * 7 + 6];
        nnzA[r] = in_sizes[r * 7 + 3];
    }
    const int *it[4], *is[4];
    const void *iv[4], *Wsp[4], *Wtp[4];
    int nnzI[4];
    for (int k = 0; k < 4; ++k) {
        it[k]  = (const int*)d_in[35 + k * 5 + 0];
        is[k]  = (const int*)d_in[35 + k * 5 + 1];
        iv[k]  = d_in[35 + k * 5 + 2];
        Wsp[k] = d_in[35 + k * 5 + 3];
        Wtp[k] = d_in[35 + k * 5 + 4];
        nnzI[k] = in_sizes[35 + k * 5 + 2];
    }

    char* ws = (char*)d_ws;
    size_t flag_off = (ws_size >= 4096) ? ((ws_size - 4) & ~(size_t)3) : 0;
    int* flag = (int*)(ws + flag_off);

    probe_dtype<<<1, 64, 0, stream>>>((const unsigned short*)x[0], flag);

    auto al16 = [](size_t v) { return (v + 15) & ~(size_t)15; };
    dim3 b256(256);
    long long base = 0;

    for (int r = 0; r < 5; ++r) {
        const int N = Ns[r];

        struct Ph { const int* rw; const int* cl; const void* vl; const void* xs;
                    const void* W; int nnz; };
        Ph ph[3]; int np = 0;
        ph[np++] = { ar[r], ac[r], av[r], x[r], Whbs[r], nnzA[r] };                       // same (cci)
        if (r < 4) ph[np++] = { it[r], is[r], iv[r], x[r + 1], Wsp[r], nnzI[r] };         // down
        if (r > 0) ph[np++] = { is[r-1], it[r-1], iv[r-1], x[r - 1], Wtp[r-1], nnzI[r-1] };// up

        // ---- batched layout: [cnt np*N][rp np*N][bsum np*256][edges...]
        size_t cntOff = 0;
        size_t rpOff  = al16((size_t)np * N * 4);
        size_t bsOff  = rpOff + al16((size_t)np * N * 4);
        size_t edOff  = al16(bsOff + (size_t)np * 256 * 4);
        size_t edSz = 0;
        for (int p = 0; p < np; ++p) edSz += al16((size_t)ph[p].nnz * 8);
        size_t need = edOff + edSz;

        if (need + 64 <= flag_off) {
            // =========== fused rank path ===========
            Seg3 B{};
            size_t ep = edOff;
            int maxnnz = 0;
            for (int p = 0; p < np; ++p) {
                B.s[p].rows = ph[p].rw;  B.s[p].cols = ph[p].cl;  B.s[p].vals = ph[p].vl;
                B.s[p].cnt  = (int*)(ws + cntOff) + (size_t)p * N;
                B.s[p].rp   = (int*)(ws + rpOff)  + (size_t)p * N;
                B.s[p].bsum = (int*)(ws + bsOff)  + (size_t)p * 256;
                B.s[p].ed   = (uint2*)(ws + ep);
                B.s[p].nnz  = ph[p].nnz;
                B.s[p].n    = N;
                ep += al16((size_t)ph[p].nnz * 8);
                if (ph[p].nnz > maxnnz) maxnnz = ph[p].nnz;
            }
            hipMemsetAsync(ws + cntOff, 0, (size_t)np * N * 4, stream);
            hist_all <<<dim3((maxnnz + 255) / 256, np), b256, 0, stream>>>(B);
            scan1_all<<<dim3((N + 1023) / 1024, np), b256, 0, stream>>>(B);
            scan2_all<<<dim3((N + 255) / 256, np), b256, 0, stream>>>(B);
            fill_all <<<dim3((maxnnz + 255) / 256, np), b256, 0, stream>>>(B, flag);

            RankArgs A{};
            for (int p = 0; p < np; ++p) {
                A.rp[p]   = B.s[p].rp;
                A.ed[p]   = B.s[p].ed;
                A.xsrc[p] = ph[p].xs;
                A.W[p]    = ph[p].W;
            }
            A.cci = cci[r]; A.Wg = Wagg[r];
            A.mbase = base; A.nrows = N; A.nph = np;
            rank_fused<<<(N + 63) / 64, b256, 0, stream>>>(A, d_out, flag);
        } else {
            // =========== per-phase fallback ===========
            for (int p = 0; p < np; ++p) {
                const int nnz = ph[p].nnz;
                size_t cOff = 0;
                size_t rOff = al16((size_t)N * 4);
                size_t bOff = rOff + al16((size_t)N * 4);
                size_t eOff = al16(bOff + 1024);
                size_t need3 = eOff + (size_t)nnz * 8;
                if (need3 + 64 <= flag_off) {
                    Seg3 B{};
                    B.s[0].rows = ph[p].rw; B.s[0].cols = ph[p].cl; B.s[0].vals = ph[p].vl;
                    B.s[0].cnt  = (int*)(ws + cOff);
                    B.s[0].rp   = (int*)(ws + rOff);
                    B.s[0].bsum = (int*)(ws + bOff);
                    B.s[0].ed   = (uint2*)(ws + eOff);
                    B.s[0].nnz  = nnz; B.s[0].n = N;
                    hipMemsetAsync(ws + cOff, 0, (size_t)N * 4, stream);
                    hist_all <<<dim3((nnz + 255) / 256, 1), b256, 0, stream>>>(B);
                    scan1_all<<<dim3((N + 1023) / 1024, 1), b256, 0, stream>>>(B);
                    scan2_all<<<dim3((N + 255) / 256, 1), b256, 0, stream>>>(B);
                    fill_all <<<dim3((nnz + 255) / 256, 1), b256, 0, stream>>>(B, flag);
                    spmm_gemm<<<(N + 63) / 64, b256, 0, stream>>>(
                        B.s[0].rp, B.s[0].ed, ph[p].xs, ph[p].W, cci[r], d_out, flag,
                        N, base, (p == 0) ? 0 : 1);
                } else {
                    long long budget = (flag_off > 256) ? (long long)((flag_off - 256) / 256) : 64;
                    budget &= ~63LL;
                    if (budget < 64) budget = 64;
                    float* acc = (float*)ws;
                    dim3 sb(64, 4);
                    for (long long r0 = 0; r0 < N; r0 += budget) {
                        int rc = (int)((N - r0 < budget) ? (N - r0) : budget);
                        hipMemsetAsync(acc, 0, (size_t)rc * 256, stream);
                        scatter_x<<<(nnz + 3) / 4, sb, 0, stream>>>(
                            ph[p].rw, ph[p].cl, ph[p].vl, ph[p].xs, flag,
                            acc, nnz, (int)r0, (int)(r0 + rc));
                        gemm_phase<<<(rc + 63) / 64, b256, 0, stream>>>(
                            acc, ph[p].W, cci[r], d_out, flag,
                            rc, r0, base, (p == 0) ? 0 : 1);
                    }
                }
            }
            finalize<<<(N + 63) / 64, b256, 0, stream>>>(d_out, Wagg[r], flag, N, base);
        }
        base += (long long)N * 64;
    }
}

// Round 3
// 1474.708 us; speedup vs baseline: 1.4367x; 1.0546x over previous
//
#include <hip/hip_runtime.h>
#include <hip/hip_bf16.h>

// ---------- helpers ----------
__device__ __forceinline__ float bf2f(unsigned short u) {
    union { unsigned int i; float f; } v;
    v.i = ((unsigned int)u) << 16;
    return v.f;
}
__device__ __forceinline__ unsigned short f2bf(float f) {
    __hip_bfloat16 h = __float2bfloat16(f);   // RNE
    return *reinterpret_cast<unsigned short*>(&h);
}
// LDS column swizzle: spreads rows across banks without +1 padding
__device__ __forceinline__ int xc(int r, int c) { return c ^ ((r & 3) << 3); }

// ---------- dtype probe: flag=0 -> bf16 inputs, flag=1 -> f32 inputs ----------
__global__ void probe_dtype(const unsigned short* __restrict__ x, int* flag) {
    if (blockIdx.x == 0 && threadIdx.x == 0) {
        int wild = 0;
        for (int i = 0; i < 512; ++i) {
            unsigned e = (x[i] >> 7) & 0xFF;
            if (e >= 0xC0) ++wild;
        }
        *flag = (wild > 0) ? 1 : 0;
    }
}

// ================= batched CSR build (gridDim.y = segment) =================
struct Seg {
    const int*  rows;
    const int*  cols;
    const void* vals;
    int*  cnt;
    int*  rp;
    int*  bsum;
    uint2* ed;
    int nnz;
    int n;
};
struct SegArr { Seg s[13]; };

// compile-time-indexed pick: avoids runtime-indexed kernarg array (scratch risk)
__device__ __forceinline__ Seg pick(const SegArr& B, int y) {
    switch (y) {
        case 0: return B.s[0];  case 1: return B.s[1];  case 2: return B.s[2];
        case 3: return B.s[3];  case 4: return B.s[4];  case 5: return B.s[5];
        case 6: return B.s[6];  case 7: return B.s[7];  case 8: return B.s[8];
        case 9: return B.s[9];  case 10: return B.s[10]; case 11: return B.s[11];
        default: return B.s[12];
    }
}

__global__ __launch_bounds__(256) void hist_all(SegArr B) {
    Seg S = pick(B, blockIdx.y);
    int e = blockIdx.x * 256 + threadIdx.x;
    if (e < S.nnz) atomicAdd(&S.cnt[S.rows[e]], 1);
}

// per-1024-chunk exclusive scan; rp gets block-local prefix, bsum[b] = block sum
__global__ __launch_bounds__(256) void scan1_all(SegArr B) {
    Seg S = pick(B, blockIdx.y);
    __shared__ int sm[256];
    const int t = threadIdx.x;
    const int base = blockIdx.x * 1024 + t * 4;
    int v[4]; int sum = 0;
#pragma unroll
    for (int j = 0; j < 4; ++j) { int i = base + j; v[j] = (i < S.n) ? S.cnt[i] : 0; sum += v[j]; }
    sm[t] = sum; __syncthreads();
    for (int off = 1; off < 256; off <<= 1) {
        int xv = (t >= off) ? sm[t - off] : 0;
        __syncthreads();
        sm[t] += xv;
        __syncthreads();
    }
    int run = sm[t] - sum;
#pragma unroll
    for (int j = 0; j < 4; ++j) { int i = base + j; if (i < S.n) S.rp[i] = run; run += v[j]; }
    if (t == 255) S.bsum[blockIdx.x] = sm[255];
}

// add cross-block offsets (parallel reduce over preceding bsum entries)
__global__ __launch_bounds__(256) void scan2_all(SegArr B) {
    Seg S = pick(B, blockIdx.y);
    __shared__ int red[256];
    const int t = threadIdx.x;
    const int g0 = blockIdx.x >> 2;   // 1024-chunk this 256-chunk belongs to
    int v = (t < g0) ? S.bsum[t] : 0;
    red[t] = v; __syncthreads();
    for (int o = 128; o; o >>= 1) { if (t < o) red[t] += red[t + o]; __syncthreads(); }
    int i = blockIdx.x * 256 + t;
    if (i < S.n) S.rp[i] += red[0];
}

// fill sorted edges; atomicAdd on rp itself -> afterwards rp[r] = END of row r
// (row r spans [r ? rp[r-1] : 0, rp[r]))
__global__ __launch_bounds__(256) void fill_all(SegArr B, const int* __restrict__ flag) {
    Seg S = pick(B, blockIdx.y);
    int e = blockIdx.x * 256 + threadIdx.x;
    if (e >= S.nnz) return;
    int r = S.rows[e];
    int pos = atomicAdd(&S.rp[r], 1);
    float v = (*flag) ? ((const float*)S.vals)[e]
                      : bf2f(((const unsigned short*)S.vals)[e]);
    uint2 ed; ed.x = (unsigned)S.cols[e]; ed.y = __float_as_uint(v);
    S.ed[pos] = ed;
}

// ================= MLP gather: 16 rows per wave, scalar edge loads =================
// Edge bounds are wave-uniform: v_readlane -> SGPR -> edge loads become s_load,
// x-row base computed in SALU; the global_load gets SGPR base + lane-only voffset.
template<int FL>
__device__ __forceinline__ void gather16(
    const int* __restrict__ rp, const uint2* __restrict__ ed,
    const void* __restrict__ x, float xsh[64][64],
    int row0, int nrows, int wv, int lane)
{
    const int rbase = row0 + wv * 16;
    int rv = 0;
    {
        int t = rbase - 1 + lane;
        if (lane <= 16 && t >= 0 && t < nrows) rv = rp[t];
    }
    const int lb = lane * (FL ? 4 : 2);   // this lane's channel byte offset
    for (int i = 0; i < 16; ++i) {
        int row = rbase + i;
        int e0 = __builtin_amdgcn_readlane(rv, i);
        int e1 = __builtin_amdgcn_readlane(rv, i + 1);
        float acc = 0.f;
        if (row < nrows) {
            for (int e = e0; e < e1; e += 8) {
                const char* xb[8]; float vv[8];
#pragma unroll
                for (int j = 0; j < 8; ++j) {
                    int idx = (e + j < e1) ? (e + j) : (e1 - 1);  // uniform clamp (SALU)
                    uint2 d = ed[idx];                            // uniform -> s_load
                    xb[j] = (const char*)x + (size_t)(d.x * (unsigned)(FL ? 256 : 128));
                    vv[j] = (e + j < e1) ? __uint_as_float(d.y) : 0.f;
                }
                float xv[8];
#pragma unroll
                for (int j = 0; j < 8; ++j)
                    xv[j] = FL ? *(const float*)(xb[j] + lb)
                               : bf2f(*(const unsigned short*)(xb[j] + lb));
#pragma unroll
                for (int j = 0; j < 8; ++j) acc = fmaf(vv[j], xv[j], acc);
            }
        }
        int lr = wv * 16 + i;
        xsh[lr][xc(lr, lane)] = acc;
    }
}

// ================= fused per-rank kernel (NPH templated: no runtime kernarg idx) ==
struct RankArgs {
    const int*   rp[3];
    const uint2* ed[3];
    const void*  xsrc[3];
    const void*  W[3];
    const void*  cci;
    const void*  Wg;
    long long    mbase;
    int          nrows;
};

template<int NPH>
__global__ __launch_bounds__(256, 4) void rank_fused(
    RankArgs A, void* __restrict__ dout, const int* __restrict__ flag)
{
    __shared__ float Ws[64][64];
    __shared__ float xsh[64][64];
    const int tid = threadIdx.x;
    const int fl = *flag;
    const int row0 = blockIdx.x * 64;
    const int wv   = __builtin_amdgcn_readfirstlane(tid >> 6);
    const int lane = tid & 63;
    const int tx = tid & 15, ty = tid >> 4;

    float C[4][4];
#pragma unroll
    for (int a = 0; a < 4; ++a)
#pragma unroll
        for (int b = 0; b < 4; ++b) C[a][b] = 0.f;

#pragma unroll
    for (int p = 0; p < NPH; ++p) {
        __syncthreads();   // previous phase done reading LDS
        if (fl) {
            const float* Wf = (const float*)A.W[p];
            for (int i = tid; i < 4096; i += 256) Ws[i >> 6][i & 63] = Wf[i];
        } else {
            const unsigned short* Wb = (const unsigned short*)A.W[p];
            for (int i = tid; i < 4096; i += 256) Ws[i >> 6][i & 63] = bf2f(Wb[i]);
        }
        if (fl) gather16<1>(A.rp[p], A.ed[p], A.xsrc[p], xsh, row0, A.nrows, wv, lane);
        else    gather16<0>(A.rp[p], A.ed[p], A.xsrc[p], xsh, row0, A.nrows, wv, lane);
        __syncthreads();

        float a4[4][4];
#pragma unroll
        for (int a = 0; a < 4; ++a)
#pragma unroll
            for (int b = 0; b < 4; ++b) a4[a][b] = 0.f;

#pragma unroll 8
        for (int k = 0; k < 64; ++k) {
            float4 w4 = *reinterpret_cast<const float4*>(&Ws[k][tx << 2]);
#pragma unroll
            for (int rr = 0; rr < 4; ++rr) {
                int r = ty + 16 * rr;
                float xv = xsh[r][xc(r, k)];
                a4[rr][0] += xv * w4.x;
                a4[rr][1] += xv * w4.y;
                a4[rr][2] += xv * w4.z;
                a4[rr][3] += xv * w4.w;
            }
        }

        if (p == 0) {   // same-rank: C += relu(T * cci)
#pragma unroll
            for (int rr = 0; rr < 4; ++rr) {
                int l = row0 + ty + 16 * rr;
                if (l >= A.nrows) continue;
                size_t co = (size_t)l * 64 + (tx << 2);
                float c4[4];
                if (fl) {
                    float4 cv = *reinterpret_cast<const float4*>(&((const float*)A.cci)[co]);
                    c4[0] = cv.x; c4[1] = cv.y; c4[2] = cv.z; c4[3] = cv.w;
                } else {
                    ushort4 cv = *reinterpret_cast<const ushort4*>(&((const unsigned short*)A.cci)[co]);
                    c4[0] = bf2f(cv.x); c4[1] = bf2f(cv.y); c4[2] = bf2f(cv.z); c4[3] = bf2f(cv.w);
                }
#pragma unroll
                for (int j = 0; j < 4; ++j) C[rr][j] += fmaxf(a4[rr][j] * c4[j], 0.f);
            }
        } else {        // C += relu(T)
#pragma unroll
            for (int rr = 0; rr < 4; ++rr)
#pragma unroll
                for (int j = 0; j < 4; ++j) C[rr][j] += fmaxf(a4[rr][j], 0.f);
        }
    }

    // ---- finalize in-block: out = relu(C @ Wg) ----
    __syncthreads();
#pragma unroll
    for (int rr = 0; rr < 4; ++rr) {
        int r = ty + 16 * rr;
#pragma unroll
        for (int j = 0; j < 4; ++j) xsh[r][xc(r, (tx << 2) + j)] = C[rr][j];
    }
    if (fl) {
        const float* Wf = (const float*)A.Wg;
        for (int i = tid; i < 4096; i += 256) Ws[i >> 6][i & 63] = Wf[i];
    } else {
        const unsigned short* Wb = (const unsigned short*)A.Wg;
        for (int i = tid; i < 4096; i += 256) Ws[i >> 6][i & 63] = bf2f(Wb[i]);
    }
    __syncthreads();

    float a4[4][4];
#pragma unroll
    for (int a = 0; a < 4; ++a)
#pragma unroll
        for (int b = 0; b < 4; ++b) a4[a][b] = 0.f;
#pragma unroll 8
    for (int k = 0; k < 64; ++k) {
        float4 w4 = *reinterpret_cast<const float4*>(&Ws[k][tx << 2]);
#pragma unroll
        for (int rr = 0; rr < 4; ++rr) {
            int r = ty + 16 * rr;
            float xv = xsh[r][xc(r, k)];
            a4[rr][0] += xv * w4.x;
            a4[rr][1] += xv * w4.y;
            a4[rr][2] += xv * w4.z;
            a4[rr][3] += xv * w4.w;
        }
    }
#pragma unroll
    for (int rr = 0; rr < 4; ++rr) {
        int l = row0 + ty + 16 * rr;
        if (l >= A.nrows) continue;
        size_t ob = (size_t)A.mbase + (size_t)l * 64 + (tx << 2);
        if (fl) {
            float4 o;
            o.x = fmaxf(a4[rr][0], 0.f); o.y = fmaxf(a4[rr][1], 0.f);
            o.z = fmaxf(a4[rr][2], 0.f); o.w = fmaxf(a4[rr][3], 0.f);
            *reinterpret_cast<float4*>(&((float*)dout)[ob]) = o;
        } else {
            ushort4 o;
            o.x = f2bf(fmaxf(a4[rr][0], 0.f)); o.y = f2bf(fmaxf(a4[rr][1], 0.f));
            o.z = f2bf(fmaxf(a4[rr][2], 0.f)); o.w = f2bf(fmaxf(a4[rr][3], 0.f));
            *reinterpret_cast<ushort4*>(&((unsigned short*)dout)[ob]) = o;
        }
    }
}

// ================= tier-C: per-phase CSR spmm (shifted rp convention) =================
__global__ __launch_bounds__(256, 4) void spmm_gemm(
    const int* __restrict__ rp, const uint2* __restrict__ edges,
    const void* __restrict__ x, const void* __restrict__ W,
    const void* __restrict__ cci, void* mout, const int* __restrict__ flag,
    int nrows, long long mbase, int mode)
{
    __shared__ float Ws[64][64];
    __shared__ float xsh[64][64];
    const int tid = threadIdx.x;
    const int fl = *flag;
    const int row0 = blockIdx.x * 64;
    const int wv   = __builtin_amdgcn_readfirstlane(tid >> 6);
    const int lane = tid & 63;

    if (fl) {
        const float* Wf = (const float*)W;
        for (int i = tid; i < 4096; i += 256) Ws[i >> 6][i & 63] = Wf[i];
    } else {
        const unsigned short* Wb = (const unsigned short*)W;
        for (int i = tid; i < 4096; i += 256) Ws[i >> 6][i & 63] = bf2f(Wb[i]);
    }
    if (fl) gather16<1>(rp, edges, x, xsh, row0, nrows, wv, lane);
    else    gather16<0>(rp, edges, x, xsh, row0, nrows, wv, lane);
    __syncthreads();

    const int tx = tid & 15, ty = tid >> 4;
    float a4[4][4];
#pragma unroll
    for (int a = 0; a < 4; ++a)
#pragma unroll
        for (int b = 0; b < 4; ++b) a4[a][b] = 0.f;

#pragma unroll 8
    for (int k = 0; k < 64; ++k) {
        float4 w4 = *reinterpret_cast<const float4*>(&Ws[k][tx << 2]);
#pragma unroll
        for (int rr = 0; rr < 4; ++rr) {
            int r = ty + 16 * rr;
            float xv = xsh[r][xc(r, k)];
            a4[rr][0] += xv * w4.x;
            a4[rr][1] += xv * w4.y;
            a4[rr][2] += xv * w4.z;
            a4[rr][3] += xv * w4.w;
        }
    }

#pragma unroll
    for (int rr = 0; rr < 4; ++rr) {
        int l = row0 + ty + 16 * rr;
        if (l >= nrows) continue;
        size_t co = (size_t)l * 64 + (tx << 2);
        size_t ob = (size_t)mbase + co;
        float t[4] = { a4[rr][0], a4[rr][1], a4[rr][2], a4[rr][3] };
        if (mode == 0) {
            float c4[4];
            if (fl) {
                float4 cv = *reinterpret_cast<const float4*>(&((const float*)cci)[co]);
                c4[0] = cv.x; c4[1] = cv.y; c4[2] = cv.z; c4[3] = cv.w;
            } else {
                ushort4 cv = *reinterpret_cast<const ushort4*>(&((const unsigned short*)cci)[co]);
                c4[0] = bf2f(cv.x); c4[1] = bf2f(cv.y); c4[2] = bf2f(cv.z); c4[3] = bf2f(cv.w);
            }
#pragma unroll
            for (int j = 0; j < 4; ++j) t[j] = fmaxf(t[j] * c4[j], 0.f);
            if (fl) {
                float4 o; o.x = t[0]; o.y = t[1]; o.z = t[2]; o.w = t[3];
                *reinterpret_cast<float4*>(&((float*)mout)[ob]) = o;
            } else {
                ushort4 o; o.x = f2bf(t[0]); o.y = f2bf(t[1]); o.z = f2bf(t[2]); o.w = f2bf(t[3]);
                *reinterpret_cast<ushort4*>(&((unsigned short*)mout)[ob]) = o;
            }
        } else {
            if (fl) {
                float* mp = (float*)mout;
                float4 ov = *reinterpret_cast<const float4*>(&mp[ob]);
                float4 o;
                o.x = ov.x + fmaxf(t[0], 0.f);
                o.y = ov.y + fmaxf(t[1], 0.f);
                o.z = ov.z + fmaxf(t[2], 0.f);
                o.w = ov.w + fmaxf(t[3], 0.f);
                *reinterpret_cast<float4*>(&mp[ob]) = o;
            } else {
                unsigned short* mp = (unsigned short*)mout;
                ushort4 ov = *reinterpret_cast<const ushort4*>(&mp[ob]);
                ushort4 o;
                o.x = f2bf(bf2f(ov.x) + fmaxf(t[0], 0.f));
                o.y = f2bf(bf2f(ov.y) + fmaxf(t[1], 0.f));
                o.z = f2bf(bf2f(ov.z) + fmaxf(t[2], 0.f));
                o.w = f2bf(bf2f(ov.w) + fmaxf(t[3], 0.f));
                *reinterpret_cast<ushort4*>(&mp[ob]) = o;
            }
        }
    }
}

// ---------- tier-C finalize: out = relu(m @ Wg), m aliases out ----------
__global__ __launch_bounds__(256) void finalize(
    void* mout, const void* __restrict__ Wg, const int* __restrict__ flag,
    int N, long long mbase)
{
    __shared__ float Ws[64][64];
    __shared__ float ms[64][65];
    const int tid = threadIdx.x;
    const int tx = tid & 15, ty = tid >> 4;
    const int fl = *flag;

    if (fl) {
        const float* Wf = (const float*)Wg;
        for (int i = tid; i < 4096; i += 256) Ws[i >> 6][i & 63] = Wf[i];
    } else {
        const unsigned short* Wb = (const unsigned short*)Wg;
        for (int i = tid; i < 4096; i += 256) Ws[i >> 6][i & 63] = bf2f(Wb[i]);
    }
    const int row0 = blockIdx.x * 64;
    for (int i = tid; i < 4096; i += 256) {
        int r = i >> 6, c = i & 63;
        int g = row0 + r;
        float v = 0.f;
        if (g < N) {
            size_t o = (size_t)mbase + (size_t)g * 64 + c;
            v = fl ? ((const float*)mout)[o] : bf2f(((const unsigned short*)mout)[o]);
        }
        ms[r][c] = v;
    }
    __syncthreads();

    float a4[4][4];
#pragma unroll
    for (int a = 0; a < 4; ++a)
#pragma unroll
        for (int b = 0; b < 4; ++b) a4[a][b] = 0.f;

#pragma unroll 8
    for (int k = 0; k < 64; ++k) {
        float4 w4 = *reinterpret_cast<const float4*>(&Ws[k][tx << 2]);
#pragma unroll
        for (int rr = 0; rr < 4; ++rr) {
            float xv = ms[ty + 16 * rr][k];
            a4[rr][0] += xv * w4.x;
            a4[rr][1] += xv * w4.y;
            a4[rr][2] += xv * w4.z;
            a4[rr][3] += xv * w4.w;
        }
    }
#pragma unroll
    for (int rr = 0; rr < 4; ++rr) {
        int g = row0 + ty + 16 * rr;
        if (g >= N) continue;
        size_t ob = (size_t)mbase + (size_t)g * 64 + (tx << 2);
        if (fl) {
            float4 o;
            o.x = fmaxf(a4[rr][0], 0.f); o.y = fmaxf(a4[rr][1], 0.f);
            o.z = fmaxf(a4[rr][2], 0.f); o.w = fmaxf(a4[rr][3], 0.f);
            *reinterpret_cast<float4*>(&((float*)mout)[ob]) = o;
        } else {
            ushort4 o;
            o.x = f2bf(fmaxf(a4[rr][0], 0.f)); o.y = f2bf(fmaxf(a4[rr][1], 0.f));
            o.z = f2bf(fmaxf(a4[rr][2], 0.f)); o.w = f2bf(fmaxf(a4[rr][3], 0.f));
            *reinterpret_cast<ushort4*>(&((unsigned short*)mout)[ob]) = o;
        }
    }
}

// ================= tier-D fallback (atomic scatter, chunked) =================
__global__ __launch_bounds__(256) void scatter_x(
    const int* __restrict__ rows, const int* __restrict__ cols,
    const void* __restrict__ vals, const void* __restrict__ x,
    const int* __restrict__ flag,
    float* __restrict__ acc, int nnz, int r0, int r1)
{
    int e = blockIdx.x * 4 + threadIdx.y;
    if (e >= nnz) return;
    int r = rows[e];
    if (r < r0 || r >= r1) return;
    int c = threadIdx.x;
    int cc = cols[e];
    const int fl = *flag;
    float v, xv;
    if (fl) {
        v  = ((const float*)vals)[e];
        xv = ((const float*)x)[(size_t)cc * 64 + c];
    } else {
        v  = bf2f(((const unsigned short*)vals)[e]);
        xv = bf2f(((const unsigned short*)x)[(size_t)cc * 64 + c]);
    }
    atomicAdd(&acc[(size_t)(r - r0) * 64 + c], v * xv);
}

__global__ __launch_bounds__(256) void gemm_phase(
    const float* __restrict__ acc,
    const void* __restrict__ W,
    const void* __restrict__ cci,
    void* mout,
    const int* __restrict__ flag,
    int n_rows, long long grow0, long long mbase, int mode)
{
    __shared__ float Ws[64][64];
    __shared__ float xs[64][65];
    const int tid = threadIdx.x;
    const int tx = tid & 15, ty = tid >> 4;
    const int fl = *flag;

    if (fl) {
        const float* Wf = (const float*)W;
        for (int i = tid; i < 4096; i += 256) Ws[i >> 6][i & 63] = Wf[i];
    } else {
        const unsigned short* Wb = (const unsigned short*)W;
        for (int i = tid; i < 4096; i += 256) Ws[i >> 6][i & 63] = bf2f(Wb[i]);
    }
    const int lrow0 = blockIdx.x * 64;
    for (int i = tid; i < 4096; i += 256) {
        int r = i >> 6, c = i & 63;
        int l = lrow0 + r;
        xs[r][c] = (l < n_rows) ? acc[(size_t)l * 64 + c] : 0.f;
    }
    __syncthreads();

    float a4[4][4];
#pragma unroll
    for (int a = 0; a < 4; ++a)
#pragma unroll
        for (int b = 0; b < 4; ++b) a4[a][b] = 0.f;

#pragma unroll 8
    for (int k = 0; k < 64; ++k) {
        float4 w4 = *reinterpret_cast<const float4*>(&Ws[k][tx << 2]);
#pragma unroll
        for (int rr = 0; rr < 4; ++rr) {
            float xv = xs[ty + 16 * rr][k];
            a4[rr][0] += xv * w4.x;
            a4[rr][1] += xv * w4.y;
            a4[rr][2] += xv * w4.z;
            a4[rr][3] += xv * w4.w;
        }
    }

#pragma unroll
    for (int rr = 0; rr < 4; ++rr) {
        int l = lrow0 + ty + 16 * rr;
        if (l >= n_rows) continue;
        long long g = grow0 + l;
        size_t co = (size_t)g * 64 + (tx << 2);
        size_t ob = (size_t)mbase + co;
        float t[4] = { a4[rr][0], a4[rr][1], a4[rr][2], a4[rr][3] };
        if (mode == 0) {
            float c4[4];
            if (fl) {
                float4 cv = *reinterpret_cast<const float4*>(&((const float*)cci)[co]);
                c4[0] = cv.x; c4[1] = cv.y; c4[2] = cv.z; c4[3] = cv.w;
            } else {
                ushort4 cv = *reinterpret_cast<const ushort4*>(&((const unsigned short*)cci)[co]);
                c4[0] = bf2f(cv.x); c4[1] = bf2f(cv.y); c4[2] = bf2f(cv.z); c4[3] = bf2f(cv.w);
            }
#pragma unroll
            for (int j = 0; j < 4; ++j) t[j] = fmaxf(t[j] * c4[j], 0.f);
            if (fl) {
                float4 o; o.x = t[0]; o.y = t[1]; o.z = t[2]; o.w = t[3];
                *reinterpret_cast<float4*>(&((float*)mout)[ob]) = o;
            } else {
                ushort4 o; o.x = f2bf(t[0]); o.y = f2bf(t[1]); o.z = f2bf(t[2]); o.w = f2bf(t[3]);
                *reinterpret_cast<ushort4*>(&((unsigned short*)mout)[ob]) = o;
            }
        } else {
            if (fl) {
                float* mp = (float*)mout;
                float4 ov = *reinterpret_cast<const float4*>(&mp[ob]);
                float4 o;
                o.x = ov.x + fmaxf(t[0], 0.f);
                o.y = ov.y + fmaxf(t[1], 0.f);
                o.z = ov.z + fmaxf(t[2], 0.f);
                o.w = ov.w + fmaxf(t[3], 0.f);
                *reinterpret_cast<float4*>(&mp[ob]) = o;
            } else {
                unsigned short* mp = (unsigned short*)mout;
                ushort4 ov = *reinterpret_cast<const ushort4*>(&mp[ob]);
                ushort4 o;
                o.x = f2bf(bf2f(ov.x) + fmaxf(t[0], 0.f));
                o.y = f2bf(bf2f(ov.y) + fmaxf(t[1], 0.f));
                o.z = f2bf(bf2f(ov.z) + fmaxf(t[2], 0.f));
                o.w = f2bf(bf2f(ov.w) + fmaxf(t[3], 0.f));
                *reinterpret_cast<ushort4*>(&mp[ob]) = o;
            }
        }
    }
}

extern "C" void kernel_launch(void* const* d_in, const int* in_sizes, int n_in,
                              void* d_out, int out_size, void* d_ws, size_t ws_size,
                              hipStream_t stream)
{
    static const int Ns[5] = {50000, 150000, 100000, 40000, 10000};

    // ---- input pointer map (setup_inputs dict order) ----
    const void *x[5], *av[5], *cci[5], *Whbs[5], *Wagg[5];
    const int *ar[5], *ac[5];
    int nnzA[5];
    for (int r = 0; r < 5; ++r) {
        x[r]    = d_in[r * 7 + 0];
        ar[r]   = (const int*)d_in[r * 7 + 1];
        ac[r]   = (const int*)d_in[r * 7 + 2];
        av[r]   = d_in[r * 7 + 3];
        cci[r]  = d_in[r * 7 + 4];
        Whbs[r] = d_in[r * 7 + 5];
        Wagg[r] = d_in[r * 7 + 6];
        nnzA[r] = in_sizes[r * 7 + 3];
    }
    const int *it[4], *is[4];
    const void *iv[4], *Wsp[4], *Wtp[4];
    int nnzI[4];
    for (int k = 0; k < 4; ++k) {
        it[k]  = (const int*)d_in[35 + k * 5 + 0];
        is[k]  = (const int*)d_in[35 + k * 5 + 1];
        iv[k]  = d_in[35 + k * 5 + 2];
        Wsp[k] = d_in[35 + k * 5 + 3];
        Wtp[k] = d_in[35 + k * 5 + 4];
        nnzI[k] = in_sizes[35 + k * 5 + 2];
    }

    char* ws = (char*)d_ws;
    size_t flag_off = (ws_size >= 4096) ? ((ws_size - 4) & ~(size_t)3) : 0;
    int* flag = (int*)(ws + flag_off);

    probe_dtype<<<1, 64, 0, stream>>>((const unsigned short*)x[0], flag);

    auto al16 = [](size_t v) { return (v + 15) & ~(size_t)15; };
    dim3 b256(256);

    // ---- phase descriptors, all ranks (order: same, down, up per rank) ----
    struct Ph { const int* rw; const int* cl; const void* vl; const void* xs;
                const void* W; int nnz; int n; };
    Ph P[13]; int seg0[5], npr[5]; int NP = 0;
    for (int r = 0; r < 5; ++r) {
        seg0[r] = NP;
        P[NP++] = { ar[r], ac[r], av[r], x[r], Whbs[r], nnzA[r], Ns[r] };
        if (r < 4) P[NP++] = { it[r], is[r], iv[r], x[r + 1], Wsp[r], nnzI[r], Ns[r] };
        if (r > 0) P[NP++] = { is[r-1], it[r-1], iv[r-1], x[r - 1], Wtp[r-1], nnzI[r-1], Ns[r] };
        npr[r] = NP - seg0[r];
    }
    long long mb[5]; { long long b = 0; for (int r = 0; r < 5; ++r) { mb[r] = b; b += (long long)Ns[r] * 64; } }

    // ---- tier A: one batched CSR build for ALL 13 phases, then 5 fused kernels ----
    long long sumN = 0; int maxN = 0, maxnnz = 0;
    for (int i = 0; i < NP; ++i) {
        sumN += P[i].n;
        if (P[i].n > maxN) maxN = P[i].n;
        if (P[i].nnz > maxnnz) maxnnz = P[i].nnz;
    }
    size_t cntOff = 0;
    size_t rpOff  = al16((size_t)sumN * 4);
    size_t bsOff  = rpOff + al16((size_t)sumN * 4);
    size_t edOff0 = bsOff + al16((size_t)NP * 256 * 4);
    size_t edSz = 0;
    for (int i = 0; i < NP; ++i) edSz += al16((size_t)P[i].nnz * 8);
    size_t needA = edOff0 + edSz;

    if (needA + 64 <= flag_off) {
        SegArr SA{};
        size_t ep = edOff0; long long cum = 0;
        for (int i = 0; i < NP; ++i) {
            SA.s[i].rows = P[i].rw; SA.s[i].cols = P[i].cl; SA.s[i].vals = P[i].vl;
            SA.s[i].cnt  = (int*)(ws + cntOff) + cum;
            SA.s[i].rp   = (int*)(ws + rpOff)  + cum;
            SA.s[i].bsum = (int*)(ws + bsOff)  + (size_t)i * 256;
            SA.s[i].ed   = (uint2*)(ws + ep);
            SA.s[i].nnz  = P[i].nnz;
            SA.s[i].n    = P[i].n;
            cum += P[i].n;
            ep += al16((size_t)P[i].nnz * 8);
        }
        hipMemsetAsync(ws + cntOff, 0, (size_t)sumN * 4, stream);
        hist_all <<<dim3((maxnnz + 255) / 256, NP), b256, 0, stream>>>(SA);
        scan1_all<<<dim3((maxN + 1023) / 1024, NP), b256, 0, stream>>>(SA);
        scan2_all<<<dim3((maxN + 255) / 256, NP), b256, 0, stream>>>(SA);
        fill_all <<<dim3((maxnnz + 255) / 256, NP), b256, 0, stream>>>(SA, flag);

        for (int r = 0; r < 5; ++r) {
            RankArgs A{};
            for (int p = 0; p < npr[r]; ++p) {
                int i = seg0[r] + p;
                A.rp[p]   = SA.s[i].rp;
                A.ed[p]   = SA.s[i].ed;
                A.xsrc[p] = P[i].xs;
                A.W[p]    = P[i].W;
            }
            A.cci = cci[r]; A.Wg = Wagg[r];
            A.mbase = mb[r]; A.nrows = Ns[r];
            int grid = (Ns[r] + 63) / 64;
            if (npr[r] == 3) rank_fused<3><<<grid, b256, 0, stream>>>(A, d_out, flag);
            else             rank_fused<2><<<grid, b256, 0, stream>>>(A, d_out, flag);
        }
        return;
    }

    // ---- tier B: per-rank batched build + fused kernel ----
    for (int r = 0; r < 5; ++r) {
        const int N = Ns[r];
        const int np = npr[r];
        size_t cOff = 0;
        size_t rOff = al16((size_t)np * N * 4);
        size_t bOff = rOff + al16((size_t)np * N * 4);
        size_t eOff = bOff + al16((size_t)np * 256 * 4);
        size_t eSz = 0;
        for (int p = 0; p < np; ++p) eSz += al16((size_t)P[seg0[r] + p].nnz * 8);
        size_t needB = eOff + eSz;

        if (needB + 64 <= flag_off) {
            SegArr SB{};
            size_t ep = eOff;
            int mxz = 0;
            for (int p = 0; p < np; ++p) {
                const Ph& q = P[seg0[r] + p];
                SB.s[p].rows = q.rw; SB.s[p].cols = q.cl; SB.s[p].vals = q.vl;
                SB.s[p].cnt  = (int*)(ws + cOff) + (size_t)p * N;
                SB.s[p].rp   = (int*)(ws + rOff) + (size_t)p * N;
                SB.s[p].bsum = (int*)(ws + bOff) + (size_t)p * 256;
                SB.s[p].ed   = (uint2*)(ws + ep);
                SB.s[p].nnz  = q.nnz;
                SB.s[p].n    = N;
                ep += al16((size_t)q.nnz * 8);
                if (q.nnz > mxz) mxz = q.nnz;
            }
            hipMemsetAsync(ws + cOff, 0, (size_t)np * N * 4, stream);
            hist_all <<<dim3((mxz + 255) / 256, np), b256, 0, stream>>>(SB);
            scan1_all<<<dim3((N + 1023) / 1024, np), b256, 0, stream>>>(SB);
            scan2_all<<<dim3((N + 255) / 256, np), b256, 0, stream>>>(SB);
            fill_all <<<dim3((mxz + 255) / 256, np), b256, 0, stream>>>(SB, flag);

            RankArgs A{};
            for (int p = 0; p < np; ++p) {
                A.rp[p]   = SB.s[p].rp;
                A.ed[p]   = SB.s[p].ed;
                A.xsrc[p] = P[seg0[r] + p].xs;
                A.W[p]    = P[seg0[r] + p].W;
            }
            A.cci = cci[r]; A.Wg = Wagg[r];
            A.mbase = mb[r]; A.nrows = N;
            int grid = (N + 63) / 64;
            if (np == 3) rank_fused<3><<<grid, b256, 0, stream>>>(A, d_out, flag);
            else         rank_fused<2><<<grid, b256, 0, stream>>>(A, d_out, flag);
            continue;
        }

        // ---- tier C/D per phase ----
        for (int p = 0; p < np; ++p) {
            const Ph& q = P[seg0[r] + p];
            const int nnz = q.nnz;
            size_t c3 = 0;
            size_t r3 = al16((size_t)N * 4);
            size_t b3 = r3 + al16((size_t)N * 4);
            size_t e3 = b3 + al16(1024);
            size_t need3 = e3 + (size_t)nnz * 8;
            if (need3 + 64 <= flag_off) {
                SegArr SC{};
                SC.s[0].rows = q.rw; SC.s[0].cols = q.cl; SC.s[0].vals = q.vl;
                SC.s[0].cnt  = (int*)(ws + c3);
                SC.s[0].rp   = (int*)(ws + r3);
                SC.s[0].bsum = (int*)(ws + b3);
                SC.s[0].ed   = (uint2*)(ws + e3);
                SC.s[0].nnz  = nnz; SC.s[0].n = N;
                hipMemsetAsync(ws + c3, 0, (size_t)N * 4, stream);
                hist_all <<<dim3((nnz + 255) / 256, 1), b256, 0, stream>>>(SC);
                scan1_all<<<dim3((N + 1023) / 1024, 1), b256, 0, stream>>>(SC);
                scan2_all<<<dim3((N + 255) / 256, 1), b256, 0, stream>>>(SC);
                fill_all <<<dim3((nnz + 255) / 256, 1), b256, 0, stream>>>(SC, flag);
                spmm_gemm<<<(N + 63) / 64, b256, 0, stream>>>(
                    SC.s[0].rp, SC.s[0].ed, q.xs, q.W, cci[r], d_out, flag,
                    N, mb[r], (p == 0) ? 0 : 1);
            } else {
                long long budget = (flag_off > 256) ? (long long)((flag_off - 256) / 256) : 64;
                budget &= ~63LL;
                if (budget < 64) budget = 64;
                float* acc = (float*)ws;
                dim3 sb(64, 4);
                for (long long r0 = 0; r0 < N; r0 += budget) {
                    int rc = (int)((N - r0 < budget) ? (N - r0) : budget);
                    hipMemsetAsync(acc, 0, (size_t)rc * 256, stream);
                    scatter_x<<<(nnz + 3) / 4, sb, 0, stream>>>(
                        q.rw, q.cl, q.vl, q.xs, flag,
                        acc, nnz, (int)r0, (int)(r0 + rc));
                    gemm_phase<<<(rc + 63) / 64, b256, 0, stream>>>(
                        acc, q.W, cci[r], d_out, flag,
                        rc, r0, mb[r], (p == 0) ? 0 : 1);
                }
            }
        }
        finalize<<<(N + 63) / 64, b256, 0, stream>>>(d_out, Wagg[r], flag, N, mb[r]);
    }
}